// Round 13
// baseline (456.425 us; speedup 1.0000x reference)
//
#include <hip/hip_runtime.h>
#include <hip/hip_bf16.h>
#include <hip/hip_fp16.h>

// QRNN: B=16, S=2048, D=1024, H=1024.  Inputs fp32, outputs fp32.
// Phase 0: convert X, W -> fp16 in ws
// Phase 1: GEMM G = X16 @ W16^T + b — 256x256 tile, BK=64, r10 relaxed 2-barrier
//          loop, 32x32x16 MFMA, T2 XOR swizzle, Gray-code reuse, XCD-swizzled
//          1-D grid, LDS-staged coalesced C-store.
// Phase 2: chunked linear scan h_t = z_t f_t + (1-f_t) h_{t-1} (32 chunks x 64), 3 passes

#define BB 16
#define SS 2048
#define DD 1024
#define HH 1024
#define N3 3072
#define CHUNK 64
#define NC (SS/CHUNK)    // 32

#define BM 256
#define BN 256
#define BK 64
#define NKT (DD/BK)      // 16 K-tiles

typedef _Float16 f16x8  __attribute__((ext_vector_type(8)));
typedef float    f32x16 __attribute__((ext_vector_type(16)));

__device__ __forceinline__ float sigm_f(float x) {
    return 1.0f / (1.0f + __expf(-x));
}
__device__ __forceinline__ float tanh_f(float x) {
    float ax = fabsf(x);
    float e  = __expf(2.0f * ax);
    float r  = 1.0f - 2.0f / (e + 1.0f);
    return copysignf(r, x);
}

// ---------------- Phase 0: fp32 -> fp16 convert (8 elems/thread) -------------
__global__ __launch_bounds__(256) void cvt_f32_f16(
    const float* __restrict__ src, __half* __restrict__ dst, int n8)
{
    int i = blockIdx.x * 256 + threadIdx.x;
    if (i >= n8) return;
    const float4* s = (const float4*)src + (size_t)i * 2;
    float4 a = s[0], b = s[1];
    f16x8 v;
    v[0] = (_Float16)a.x; v[1] = (_Float16)a.y; v[2] = (_Float16)a.z; v[3] = (_Float16)a.w;
    v[4] = (_Float16)b.x; v[5] = (_Float16)b.y; v[6] = (_Float16)b.z; v[7] = (_Float16)b.w;
    *((f16x8*)dst + i) = v;
}

// ---------------- GEMM: 256^2, 32x32x16 MFMA, r10 structure ------------------
__global__ __launch_bounds__(512) void gemm_gates8(
    const __half* __restrict__ Xs,      // [rows][1024] fp16 (slab-local)
    const __half* __restrict__ W16,     // [3072][1024] fp16
    const float*  __restrict__ bias,    // [3072] fp32
    __half* __restrict__ G,             // [rows][3072] fp16
    int mtiles)                         // = bs*8 (M-tiles); N-tiles = 12
{
    __shared__ __half As[2][BM * BK] __attribute__((aligned(16)));  // 64 KiB
    __shared__ __half Bs[2][BN * BK] __attribute__((aligned(16)));  // 64 KiB

    // XCD swizzle (T1, bijective: gridDim.x = mtiles*12, divisible by 8):
    // consecutive in-XCD blocks walk M within an N-band -> W panel L2-resident.
    const int q   = (mtiles * 3) >> 1;              // nwg/8
    const int sb  = (blockIdx.x & 7) * q + (blockIdx.x >> 3);
    const int m0  = (sb % mtiles) * BM;
    const int n0  = (sb / mtiles) * BN;

    const int t   = threadIdx.x;
    const int wid = t >> 6;       // 0..7
    const int l   = t & 63;
    const int wr  = wid >> 2;     // 0..1 (M)
    const int wc  = wid & 3;      // 0..3 (N)
    const int l31 = l & 31;       // row/col within 32-fragment
    const int lh  = l >> 5;       // k-half (0: k0-7, 1: k8-15)
    const int cs  = l & 7;        // read-side swizzle key (row&7 == l&7)

    f32x16 acc[4][2];
    #pragma unroll
    for (int m = 0; m < 4; ++m)
        #pragma unroll
        for (int n = 0; n < 2; ++n)
            #pragma unroll
            for (int e = 0; e < 16; ++e)
                acc[m][n][e] = 0.f;

    // staging: issue j covers rows j*64..j*64+63; lane -> row j*64+wid*8+l/8.
    // T2 write-side: global 16B-chunk = (l&7) ^ (row&7); LDS dest linear.
    const int srow = wid * 8 + (l >> 3);
    const int scol = (((l & 7) ^ ((l >> 3) & 7)) * 8);
    const __half* Xb = Xs  + (size_t)(m0 + srow) * DD + scol;
    const __half* Wb = W16 + (size_t)(n0 + srow) * DD + scol;

#define ISSUE_A(slot, j, kt) \
    __builtin_amdgcn_global_load_lds( \
        (const __attribute__((address_space(1))) void*)(Xb + (size_t)(j) * 64 * DD + (kt) * BK), \
        (__attribute__((address_space(3))) void*)(&As[slot][(j) * 4096 + wid * 512]), 16, 0, 0)
#define ISSUE_B(slot, j, kt) \
    __builtin_amdgcn_global_load_lds( \
        (const __attribute__((address_space(1))) void*)(Wb + (size_t)(j) * 64 * DD + (kt) * BK), \
        (__attribute__((address_space(3))) void*)(&Bs[slot][(j) * 4096 + wid * 512]), 16, 0, 0)

    // fragment reads (T2 read-side: chunk = (ks*2 + lh) ^ (row&7), row&7 == cs)
    // A-operand 32x32x16: lane l31 = row, lh = k-half, 8 contiguous k per lane.
#define READ_A(ad, mh) \
    _Pragma("unroll") \
    for (int mf2 = 0; mf2 < 2; ++mf2) \
        _Pragma("unroll") \
        for (int ks = 0; ks < 4; ++ks) \
            ad[mf2][ks] = *(const f16x8*)(Ab + ((wr * 128 + ((mh) * 2 + mf2) * 32 + l31) * BK \
                                                + (((ks * 2 + lh) ^ cs) * 8)))
#define READ_B(bd, nf) \
    _Pragma("unroll") \
    for (int ks = 0; ks < 4; ++ks) \
        bd[ks] = *(const f16x8*)(Bb + ((wc * 64 + (nf) * 32 + l31) * BK \
                                       + (((ks * 2 + lh) ^ cs) * 8)))

    // MFMA cluster: ks outer, mf2 inner (2 independent between RAW partners)
#define MFMA_Q(ad, mh, nf, bd) \
    __builtin_amdgcn_sched_barrier(0); \
    __builtin_amdgcn_s_setprio(1); \
    _Pragma("unroll") \
    for (int ks = 0; ks < 4; ++ks) \
        _Pragma("unroll") \
        for (int mf2 = 0; mf2 < 2; ++mf2) \
            acc[(mh) * 2 + mf2][nf] = __builtin_amdgcn_mfma_f32_32x32x16_f16( \
                ad[mf2][ks], bd[ks], acc[(mh) * 2 + mf2][nf], 0, 0, 0); \
    __builtin_amdgcn_s_setprio(0); \
    __builtin_amdgcn_sched_barrier(0)

    // prologue: stage tile 0 into slot 0
    ISSUE_A(0, 0, 0); ISSUE_A(0, 1, 0); ISSUE_A(0, 2, 0); ISSUE_A(0, 3, 0);
    ISSUE_B(0, 0, 0); ISSUE_B(0, 1, 0); ISSUE_B(0, 2, 0); ISSUE_B(0, 3, 0);

    for (int kt = 0; kt < NKT; ++kt) {
        const int cur = kt & 1, nxt = cur ^ 1;
        const __half* Ab = As[cur];
        const __half* Bb = Bs[cur];

        // boundary: issue A-half of next tile, counted wait, sync
        if (kt + 1 < NKT) {
            ISSUE_A(nxt, 0, kt + 1); ISSUE_A(nxt, 1, kt + 1);
            ISSUE_A(nxt, 2, kt + 1); ISSUE_A(nxt, 3, kt + 1);
            asm volatile("s_waitcnt vmcnt(4)" ::: "memory");
        } else {
            asm volatile("s_waitcnt vmcnt(0)" ::: "memory");
        }
        __builtin_amdgcn_s_barrier();

        f16x8 a0[2][4], a1[2][4], b0[4], b1[4];

        // P0: read A(mh0)+B(nf0), compute Q(0,0)
        READ_A(a0, 0); READ_B(b0, 0);
        asm volatile("s_waitcnt lgkmcnt(0)" ::: "memory");
        MFMA_Q(a0, 0, 0, b0);

        // P1: read B(nf1); stage B-half of next tile; Q(0,1)
        READ_B(b1, 1);
        if (kt + 1 < NKT) {
            ISSUE_B(nxt, 0, kt + 1); ISSUE_B(nxt, 1, kt + 1);
            ISSUE_B(nxt, 2, kt + 1); ISSUE_B(nxt, 3, kt + 1);
        }
        asm volatile("s_waitcnt lgkmcnt(0)" ::: "memory");
        MFMA_Q(a0, 0, 1, b1);

        // P2: read A(mh1), reuse b1 -> Q(1,1)
        READ_A(a1, 1);
        asm volatile("s_waitcnt lgkmcnt(0)" ::: "memory");
        MFMA_Q(a1, 1, 1, b1);

        // P3: reuse a1 + b0 -> Q(1,0), no reads
        MFMA_Q(a1, 1, 0, b0);

        // tile-end: all reads of cur slot done before next boundary's DMA
        __builtin_amdgcn_s_barrier();
    }
#undef MFMA_Q
#undef READ_A
#undef READ_B
#undef ISSUE_A
#undef ISSUE_B

    // ---- epilogue: LDS-staged coalesced C-store (reuse As, 4 rounds x 64 rows)
    // 32x32 C/D layout: col = lane&31, row = (reg&3) + 8*(reg>>2) + 4*(lane>>5)
    __half* sh = &As[0][0];     // 64*264 = 16896 halves <= 32768 available
    float bvn[2];
    #pragma unroll
    for (int nf = 0; nf < 2; ++nf) bvn[nf] = bias[n0 + wc * 64 + nf * 32 + l31];

    const int row_l = t >> 3;       // 0..63
    const int chunk = t & 7;        // 64B chunks

    #pragma unroll
    for (int r = 0; r < 4; ++r) {
        if (wr == (r >> 1)) {
            #pragma unroll
            for (int mf2 = 0; mf2 < 2; ++mf2) {
                const int mf = (r & 1) * 2 + mf2;
                #pragma unroll
                for (int nf = 0; nf < 2; ++nf) {
                    #pragma unroll
                    for (int reg = 0; reg < 16; ++reg) {
                        const int rl = mf2 * 32 + (reg & 3) + 8 * (reg >> 2) + 4 * lh;
                        sh[rl * 264 + wc * 64 + nf * 32 + l31] =
                            __float2half(acc[mf][nf][reg] + bvn[nf]);
                    }
                }
            }
        }
        __builtin_amdgcn_s_barrier();
        {
            const __half* src = sh + row_l * 264 + chunk * 32;
            __half* dst = G + (size_t)(m0 + r * 64 + row_l) * N3 + n0 + chunk * 32;
            #pragma unroll
            for (int k = 0; k < 4; ++k)
                *(f16x8*)(dst + k * 8) = *(const f16x8*)(src + k * 8);
        }
        __builtin_amdgcn_s_barrier();
    }
}

// ---------------- Pass 1: per-chunk local scan -> (A, F) ---------------------
__global__ __launch_bounds__(256) void scan_pass1(
    const __half* __restrict__ G,
    float* __restrict__ Ac, float* __restrict__ Fc)
{
    const int flat = blockIdx.x * 256 + threadIdx.x;
    const int h  = flat & (HH - 1);
    const int c  = (flat >> 10) & (NC - 1);
    const int lb = flat >> 15;

    const __half* g = G + (size_t)(lb * SS + c * CHUNK) * N3 + h;
    float A = 0.f, F = 1.f;
    for (int s = 0; s < CHUNK; ++s) {
        float z = __half2float(g[0]);
        float f = __half2float(g[HH]);
        g += N3;
        float ft = sigm_f(f);
        float fp = 1.f - ft;
        A = tanh_f(z) * ft + fp * A;
        F *= fp;
    }
    Ac[flat] = A;
    Fc[flat] = F;
}

// ---------------- Pass 2: sequential chunk combine, emit h_in + c_last -------
__global__ __launch_bounds__(256) void scan_pass2(
    const float* __restrict__ Ac, const float* __restrict__ Fc,
    float* __restrict__ Hin, float* __restrict__ c_last)
{
    const int flat = blockIdx.x * 256 + threadIdx.x;   // lb*HH + h
    const int lb = flat >> 10;
    const int h  = flat & (HH - 1);
    float hc = 0.f;
    for (int c = 0; c < NC; ++c) {
        const size_t idx = (size_t)(lb * NC + c) * HH + h;
        Hin[idx] = hc;
        hc = Ac[idx] + Fc[idx] * hc;
    }
    c_last[flat] = hc;
}

// ---------------- Pass 3: replay with correct h_in, fuse output gate ---------
__global__ __launch_bounds__(256) void scan_pass3(
    const __half* __restrict__ G, const float* __restrict__ Hin,
    float* __restrict__ out)
{
    const int flat = blockIdx.x * 256 + threadIdx.x;
    const int h  = flat & (HH - 1);
    const int c  = (flat >> 10) & (NC - 1);
    const int lb = flat >> 15;

    const __half* g = G + (size_t)(lb * SS + c * CHUNK) * N3 + h;
    float* o = out + (size_t)(lb * SS + c * CHUNK) * HH + h;
    float hc = Hin[flat];
    for (int s = 0; s < CHUNK; ++s) {
        float z  = __half2float(g[0]);
        float f  = __half2float(g[HH]);
        float og = __half2float(g[2 * HH]);
        g += N3;
        float ft = sigm_f(f);
        hc = tanh_f(z) * ft + (1.f - ft) * hc;
        *o = hc * sigm_f(og);
        o += HH;
    }
}

extern "C" void kernel_launch(void* const* d_in, const int* in_sizes, int n_in,
                              void* d_out, int out_size, void* d_ws, size_t ws_size,
                              hipStream_t stream) {
    // re-key inputs by element count for order safety
    const float* X    = (const float*)d_in[0];
    const float* W    = (const float*)d_in[1];
    const float* bias = (const float*)d_in[2];
    for (int i = 0; i < n_in && i < 3; ++i) {
        if      (in_sizes[i] == BB * SS * DD) X    = (const float*)d_in[i];
        else if (in_sizes[i] == N3 * DD)      W    = (const float*)d_in[i];
        else if (in_sizes[i] == N3)           bias = (const float*)d_in[i];
    }
    float* out = (float*)d_out;                           // [B,S,H] ++ [B,1,H] fp32
    float* c_last_base = out + (size_t)BB * SS * HH;

    // ws layout: W16 | X16(nb) | G(nb) | Ac/Fc/Hin(nb)
    const size_t w16_b   = (size_t)N3 * DD * sizeof(__half);          //  6.29 MB
    const size_t per_b_x = (size_t)SS * DD * sizeof(__half);          //  4.19 MB
    const size_t per_b_g = (size_t)SS * N3 * sizeof(__half);          // 12.58 MB
    const size_t per_b_s = (size_t)NC * HH * sizeof(float) * 3;       //  0.39 MB
    int nb = 1;
    for (int cand = BB; cand >= 1; --cand) {
        if (w16_b + (size_t)cand * (per_b_x + per_b_g + per_b_s) <= ws_size) {
            nb = cand; break;
        }
    }
    if (nb > 8) nb = 8;   // 2 slabs: exact 768-block GEMM rounds + ~L3-resident G

    __half* W16 = (__half*)d_ws;
    __half* X16 = (__half*)((char*)W16 + w16_b);
    __half* G   = (__half*)((char*)X16 + (size_t)nb * per_b_x);
    float*  Ac  = (float*)((char*)G + (size_t)nb * per_b_g);
    float*  Fc  = Ac + (size_t)nb * NC * HH;
    float*  Hin = Fc + (size_t)nb * NC * HH;

    // W convert (once)
    {
        const int n8 = (N3 * DD) / 8;
        cvt_f32_f16<<<(n8 + 255) / 256, 256, 0, stream>>>(W, W16, n8);
    }

    for (int b0 = 0; b0 < BB; b0 += nb) {
        const int bs = (b0 + nb <= BB) ? nb : (BB - b0);

        const int n8x = (bs * SS * DD) / 8;
        cvt_f32_f16<<<(n8x + 255) / 256, 256, 0, stream>>>(
            X + (size_t)b0 * SS * DD, X16, n8x);

        const int mtiles = bs * (SS / BM);     // bs*8
        gemm_gates8<<<mtiles * 12, 512, 0, stream>>>(X16, W16, bias, G, mtiles);

        scan_pass1<<<(bs * NC * HH) / 256, 256, 0, stream>>>(G, Ac, Fc);
        scan_pass2<<<(bs * HH) / 256, 256, 0, stream>>>(Ac, Fc, Hin,
                                                        c_last_base + (size_t)b0 * HH);
        scan_pass3<<<(bs * NC * HH) / 256, 256, 0, stream>>>(G, Hin,
                                                             out + (size_t)b0 * SS * HH);
    }
}

// Round 14
// 450.134 us; speedup vs baseline: 1.0140x; 1.0140x over previous
//
#include <hip/hip_runtime.h>
#include <hip/hip_bf16.h>
#include <hip/hip_fp16.h>

// QRNN: B=16, S=2048, D=1024, H=1024.  Inputs fp32, outputs fp32.
// Phase 0: convert X, W -> fp16 in ws
// Phase 1: GEMM G = X16 @ W16^T + b — r6-verified m97 structure (128x128 tile,
//          BK=32, 4 waves, ~3 blocks/CU wave-slip) + both-sides XOR bank swizzle
//          + LDS-staged coalesced epilogue.  No XCD swizzle (r13: hurt L3 locality).
// Phase 2: chunked linear scan h_t = z_t f_t + (1-f_t) h_{t-1} (32 chunks x 64), 3 passes

#define BB 16
#define SS 2048
#define DD 1024
#define HH 1024
#define N3 3072
#define CHUNK 64
#define NC (SS/CHUNK)    // 32

typedef _Float16 f16x8 __attribute__((ext_vector_type(8)));
typedef float    f32x4 __attribute__((ext_vector_type(4)));

__device__ __forceinline__ float sigm_f(float x) {
    return 1.0f / (1.0f + __expf(-x));
}
__device__ __forceinline__ float tanh_f(float x) {
    float ax = fabsf(x);
    float e  = __expf(2.0f * ax);
    float r  = 1.0f - 2.0f / (e + 1.0f);
    return copysignf(r, x);
}

// ---------------- Phase 0: fp32 -> fp16 convert (8 elems/thread) -------------
__global__ __launch_bounds__(256) void cvt_f32_f16(
    const float* __restrict__ src, __half* __restrict__ dst, int n8)
{
    int i = blockIdx.x * 256 + threadIdx.x;
    if (i >= n8) return;
    const float4* s = (const float4*)src + (size_t)i * 2;
    float4 a = s[0], b = s[1];
    f16x8 v;
    v[0] = (_Float16)a.x; v[1] = (_Float16)a.y; v[2] = (_Float16)a.z; v[3] = (_Float16)a.w;
    v[4] = (_Float16)b.x; v[5] = (_Float16)b.y; v[6] = (_Float16)b.z; v[7] = (_Float16)b.w;
    *((f16x8*)dst + i) = v;
}

// ---------------- GEMM: 128x128, BK=32, 4 waves, swizzled, coalesced C -------
__global__ __launch_bounds__(256) void gemm_gates(
    const __half* __restrict__ Xs,      // [rows][1024] fp16 (slab-local)
    const __half* __restrict__ W16,     // [3072][1024] fp16
    const float*  __restrict__ bias,    // [3072] fp32
    __half* __restrict__ G)             // [rows][3072] fp16
{
    // one 16 KiB buffer: K-loop carves As/Bs; epilogue reuses the whole thing
    __shared__ __half smem[8192] __attribute__((aligned(16)));
    __half* As = smem;          // [128 rows][32 k], 64 B rows
    __half* Bs = smem + 4096;

    const int t  = threadIdx.x;
    const int w  = t >> 6;
    const int l  = t & 63;
    const int m0 = blockIdx.y * 128;
    const int n0 = blockIdx.x * 128;
    const int wm = w >> 1;
    const int wn = w & 1;
    const int cl = l & 15;
    const int kg = l >> 4;

    f32x4 acc[4][4];
    #pragma unroll
    for (int m = 0; m < 4; ++m)
        #pragma unroll
        for (int n = 0; n < 4; ++n)
            acc[m][n] = f32x4{0.f, 0.f, 0.f, 0.f};

    // staging (r6-verified geometry): wave w stages 1024B chunks {w, w+4};
    // lane l -> row c*16 + l/4, LDS pos (l&3).
    // Bank swizzle f(r) = (r&3)^((r>>2)&3): LDS pos p holds global chunk p^f(r).
    // Pre-swizzled SOURCE chunk = (l&3) ^ f(row);  row&3=(l>>2)&3, (row>>2)&3=(l>>4)&3.
    const int c0 = w;
    const int c1 = w + 4;
    const int rA0 = c0 * 16 + (l >> 2);
    const int rA1 = c1 * 16 + (l >> 2);
    const int ck  = (((l & 3) ^ ((l >> 2) & 3) ^ ((l >> 4) & 3)) * 8);

    const __half* Xb = Xs  + (size_t)m0 * DD;
    const __half* Wb = W16 + (size_t)n0 * DD;

    // read-side swizzled chunk (constant per lane): fragment row = base + cl,
    // f(row) = (cl&3)^((cl>>2)&3); logical chunk = kg.
    const int rpos = (kg ^ (cl & 3) ^ ((cl >> 2) & 3)) * 8;   // halves offset

    for (int k0 = 0; k0 < DD; k0 += 32) {
        __builtin_amdgcn_global_load_lds(
            (const __attribute__((address_space(1))) void*)(Xb + (size_t)rA0 * DD + k0 + ck),
            (__attribute__((address_space(3))) void*)((char*)As + c0 * 1024), 16, 0, 0);
        __builtin_amdgcn_global_load_lds(
            (const __attribute__((address_space(1))) void*)(Xb + (size_t)rA1 * DD + k0 + ck),
            (__attribute__((address_space(3))) void*)((char*)As + c1 * 1024), 16, 0, 0);
        __builtin_amdgcn_global_load_lds(
            (const __attribute__((address_space(1))) void*)(Wb + (size_t)rA0 * DD + k0 + ck),
            (__attribute__((address_space(3))) void*)((char*)Bs + c0 * 1024), 16, 0, 0);
        __builtin_amdgcn_global_load_lds(
            (const __attribute__((address_space(1))) void*)(Wb + (size_t)rA1 * DD + k0 + ck),
            (__attribute__((address_space(3))) void*)((char*)Bs + c1 * 1024), 16, 0, 0);
        __syncthreads();   // drains vmcnt -> tiles visible (m97 structure)

        f16x8 a[4], b[4];
        #pragma unroll
        for (int m = 0; m < 4; ++m)
            a[m] = *(const f16x8*)(As + (wm * 64 + m * 16 + cl) * 32 + rpos);
        #pragma unroll
        for (int n = 0; n < 4; ++n)
            b[n] = *(const f16x8*)(Bs + (wn * 64 + n * 16 + cl) * 32 + rpos);

        #pragma unroll
        for (int m = 0; m < 4; ++m)
            #pragma unroll
            for (int n = 0; n < 4; ++n)
                acc[m][n] = __builtin_amdgcn_mfma_f32_16x16x32_f16(
                    a[m], b[n], acc[m][n], 0, 0, 0);
        __syncthreads();   // protect LDS before next stage
    }

    // ---- epilogue: LDS-staged coalesced C-store (4 rounds x 32 rows, pitch 136)
    // C/D layout (r6-verified): col = lane&15, row = (lane>>4)*4 + reg
    __half* sh = smem;          // 32*136 = 4352 halves <= 8192
    float bv[4];
    #pragma unroll
    for (int n = 0; n < 4; ++n) bv[n] = bias[n0 + wn * 64 + n * 16 + cl];

    const int row_s = t >> 3;       // 0..31
    const int chk   = t & 7;        // 32B chunks

    #pragma unroll
    for (int r = 0; r < 4; ++r) {
        if (wm == (r >> 1)) {
            #pragma unroll
            for (int mm = 0; mm < 2; ++mm) {
                const int m  = (r & 1) * 2 + mm;
                const int rl = mm * 16 + kg * 4;
                #pragma unroll
                for (int n = 0; n < 4; ++n) {
                    #pragma unroll
                    for (int i = 0; i < 4; ++i) {
                        sh[(rl + i) * 136 + wn * 64 + n * 16 + cl] =
                            __float2half(acc[m][n][i] + bv[n]);
                    }
                }
            }
        }
        __syncthreads();
        {
            const __half* src = sh + row_s * 136 + chk * 16;
            __half* dst = G + (size_t)(m0 + r * 32 + row_s) * N3 + n0 + chk * 16;
            *(f16x8*)(dst)     = *(const f16x8*)(src);
            *(f16x8*)(dst + 8) = *(const f16x8*)(src + 8);
        }
        __syncthreads();
    }
}

// ---------------- Pass 1: per-chunk local scan -> (A, F) ---------------------
__global__ __launch_bounds__(256) void scan_pass1(
    const __half* __restrict__ G,
    float* __restrict__ Ac, float* __restrict__ Fc)
{
    const int flat = blockIdx.x * 256 + threadIdx.x;
    const int h  = flat & (HH - 1);
    const int c  = (flat >> 10) & (NC - 1);
    const int lb = flat >> 15;

    const __half* g = G + (size_t)(lb * SS + c * CHUNK) * N3 + h;
    float A = 0.f, F = 1.f;
    for (int s = 0; s < CHUNK; ++s) {
        float z = __half2float(g[0]);
        float f = __half2float(g[HH]);
        g += N3;
        float ft = sigm_f(f);
        float fp = 1.f - ft;
        A = tanh_f(z) * ft + fp * A;
        F *= fp;
    }
    Ac[flat] = A;
    Fc[flat] = F;
}

// ---------------- Pass 2: sequential chunk combine, emit h_in + c_last -------
__global__ __launch_bounds__(256) void scan_pass2(
    const float* __restrict__ Ac, const float* __restrict__ Fc,
    float* __restrict__ Hin, float* __restrict__ c_last)
{
    const int flat = blockIdx.x * 256 + threadIdx.x;   // lb*HH + h
    const int lb = flat >> 10;
    const int h  = flat & (HH - 1);
    float hc = 0.f;
    for (int c = 0; c < NC; ++c) {
        const size_t idx = (size_t)(lb * NC + c) * HH + h;
        Hin[idx] = hc;
        hc = Ac[idx] + Fc[idx] * hc;
    }
    c_last[flat] = hc;
}

// ---------------- Pass 3: replay with correct h_in, fuse output gate ---------
__global__ __launch_bounds__(256) void scan_pass3(
    const __half* __restrict__ G, const float* __restrict__ Hin,
    float* __restrict__ out)
{
    const int flat = blockIdx.x * 256 + threadIdx.x;
    const int h  = flat & (HH - 1);
    const int c  = (flat >> 10) & (NC - 1);
    const int lb = flat >> 15;

    const __half* g = G + (size_t)(lb * SS + c * CHUNK) * N3 + h;
    float* o = out + (size_t)(lb * SS + c * CHUNK) * HH + h;
    float hc = Hin[flat];
    for (int s = 0; s < CHUNK; ++s) {
        float z  = __half2float(g[0]);
        float f  = __half2float(g[HH]);
        float og = __half2float(g[2 * HH]);
        g += N3;
        float ft = sigm_f(f);
        hc = tanh_f(z) * ft + (1.f - ft) * hc;
        *o = hc * sigm_f(og);
        o += HH;
    }
}

extern "C" void kernel_launch(void* const* d_in, const int* in_sizes, int n_in,
                              void* d_out, int out_size, void* d_ws, size_t ws_size,
                              hipStream_t stream) {
    // re-key inputs by element count for order safety
    const float* X    = (const float*)d_in[0];
    const float* W    = (const float*)d_in[1];
    const float* bias = (const float*)d_in[2];
    for (int i = 0; i < n_in && i < 3; ++i) {
        if      (in_sizes[i] == BB * SS * DD) X    = (const float*)d_in[i];
        else if (in_sizes[i] == N3 * DD)      W    = (const float*)d_in[i];
        else if (in_sizes[i] == N3)           bias = (const float*)d_in[i];
    }
    float* out = (float*)d_out;                           // [B,S,H] ++ [B,1,H] fp32
    float* c_last_base = out + (size_t)BB * SS * HH;

    // ws layout: W16 | X16(nb) | G(nb) | Ac/Fc/Hin(nb)
    const size_t w16_b   = (size_t)N3 * DD * sizeof(__half);          //  6.29 MB
    const size_t per_b_x = (size_t)SS * DD * sizeof(__half);          //  4.19 MB
    const size_t per_b_g = (size_t)SS * N3 * sizeof(__half);          // 12.58 MB
    const size_t per_b_s = (size_t)NC * HH * sizeof(float) * 3;       //  0.39 MB
    int nb = 1;
    for (int cand = BB; cand >= 1; --cand) {
        if (w16_b + (size_t)cand * (per_b_x + per_b_g + per_b_s) <= ws_size) {
            nb = cand; break;
        }
    }
    if (nb > 8) nb = 8;   // 2 slabs: G ~100 MB/slab stays L3-friendly

    __half* W16 = (__half*)d_ws;
    __half* X16 = (__half*)((char*)W16 + w16_b);
    __half* G   = (__half*)((char*)X16 + (size_t)nb * per_b_x);
    float*  Ac  = (float*)((char*)G + (size_t)nb * per_b_g);
    float*  Fc  = Ac + (size_t)nb * NC * HH;
    float*  Hin = Fc + (size_t)nb * NC * HH;

    // W convert (once)
    {
        const int n8 = (N3 * DD) / 8;
        cvt_f32_f16<<<(n8 + 255) / 256, 256, 0, stream>>>(W, W16, n8);
    }

    for (int b0 = 0; b0 < BB; b0 += nb) {
        const int bs = (b0 + nb <= BB) ? nb : (BB - b0);

        const int n8x = (bs * SS * DD) / 8;
        cvt_f32_f16<<<(n8x + 255) / 256, 256, 0, stream>>>(
            X + (size_t)b0 * SS * DD, X16, n8x);

        dim3 gg(N3 / 128, bs * (SS / 128));   // (24, bs*16)
        gemm_gates<<<gg, 256, 0, stream>>>(X16, W16, bias, G);

        scan_pass1<<<(bs * NC * HH) / 256, 256, 0, stream>>>(G, Ac, Fc);
        scan_pass2<<<(bs * HH) / 256, 256, 0, stream>>>(Ac, Fc, Hin,
                                                        c_last_base + (size_t)b0 * HH);
        scan_pass3<<<(bs * NC * HH) / 256, 256, 0, stream>>>(G, Hin,
                                                             out + (size_t)b0 * SS * HH);
    }
}